// Round 15
// baseline (106.939 us; speedup 1.0000x reference)
//
#include <hip/hip_runtime.h>
#include <cstdint>
#include <cstddef>

// ---------- types ----------
typedef __attribute__((ext_vector_type(8))) short short8;
typedef __attribute__((ext_vector_type(4))) float f32x4;
typedef __attribute__((ext_vector_type(4))) unsigned short ushort4v;
typedef unsigned short ushort_t;

union PFrag { unsigned int w[4]; short8 v; };

__device__ __forceinline__ ushort_t f2bf(float f) {
  unsigned int u = __builtin_bit_cast(unsigned int, f);
  u += 0x7FFFu + ((u >> 16) & 1u);   // RNE; inputs finite
  return (ushort_t)(u >> 16);
}

__device__ __forceinline__ void gload16(const void* g, void* l) {
  __builtin_amdgcn_global_load_lds(
      (const __attribute__((address_space(1))) unsigned int*)g,
      (__attribute__((address_space(3))) unsigned int*)l, 16, 0, 0);
}

// ---------- merged prep kernel (round-11 proven) ----------
__global__ __launch_bounds__(256) void prep_kernel(
    const float* __restrict__ x, ushort_t* __restrict__ xb,
    const float* __restrict__ Wq, const float* __restrict__ Wk,
    const float* __restrict__ Wv, const float* __restrict__ Wo,
    const float* __restrict__ bq, const float* __restrict__ bk,
    const float* __restrict__ bv, ushort_t* __restrict__ Wt,
    float* __restrict__ bqkv) {
  __shared__ float tile[32][33];
  const int t = threadIdx.x;
  if (blockIdx.x < 8192) {
    const int i = (blockIdx.x * 256 + t) * 4;
    const float4 v = *reinterpret_cast<const float4*>(x + i);
    ushort4v r = { f2bf(v.x), f2bf(v.y), f2bf(v.z), f2bf(v.w) };
    *reinterpret_cast<ushort4v*>(xb + i) = r;
    return;
  }
  const int bid = blockIdx.x - 8192;          // 0..2559
  const int tn = bid % 80, tk = bid / 80;
  if (tk == 0) {
    const int u = tn * 256 + t;
    if (u < 1536) bqkv[u] = (u < 1024) ? bq[u] : (u < 1280) ? bk[u - 1024] : bv[u - 1280];
  }
  const int n0 = tn * 32;
  const float* W; int ldn, nloc;
  if      (n0 < 1024) { W = Wq; ldn = 1024; nloc = n0; }
  else if (n0 < 1280) { W = Wk; ldn = 256;  nloc = n0 - 1024; }
  else if (n0 < 1536) { W = Wv; ldn = 256;  nloc = n0 - 1280; }
  else                { W = Wo; ldn = 1024; nloc = n0 - 1536; }
  const int sr = t >> 3, sc = (t & 7) * 4;
  const float4 v = *reinterpret_cast<const float4*>(W + (size_t)(tk * 32 + sr) * ldn + nloc + sc);
  tile[sr][sc] = v.x; tile[sr][sc + 1] = v.y; tile[sr][sc + 2] = v.z; tile[sr][sc + 3] = v.w;
  __syncthreads();
  const int wr = t >> 3, wc = (t & 7) * 4;
  ushort4v o = { f2bf(tile[wc][wr]), f2bf(tile[wc + 1][wr]),
                 f2bf(tile[wc + 2][wr]), f2bf(tile[wc + 3][wr]) };
  *reinterpret_cast<ushort4v*>(Wt + (size_t)(n0 + wr) * 1024 + tk * 32 + wc) = o;
}

// ---------- QKV GEMM: BARRIER-FREE per-wave self-paced staging ----------
// Block tile 128x128, 4 waves (2x2), per-wave 64x64 (acc[4][4]), BK=32.
// Each wave stages its OWN A 64x32 + B 64x32 tiles via global_load_lds into
// a private 16 KB LDS region (2 stages of 8 KB); counted per-wave vmcnt(8);
// tile t+2 issued AFTER the MFMA cluster consumed tile t's fragments
// (register deps force lgkm waits first -> no LDS write-after-read hazard;
// VM retirement is in issue order so vmcnt(8) = "tile t landed").
// ZERO barriers: waves drift and cover each other's stalls (m114 mechanism).
// LDS 64 KB -> 2 blocks/CU = 8 independent wave-streams per CU.
__global__ __launch_bounds__(256, 2) void gemm_qkv_kernel(
    const ushort_t* __restrict__ A, const ushort_t* __restrict__ Bt,
    const float* __restrict__ bias,
    ushort_t* __restrict__ Qb, ushort_t* __restrict__ Kb, ushort_t* __restrict__ Vt)
{
  __shared__ __align__(16) char LdsB[65536];
  const int xcd = blockIdx.x & 7, ii = blockIdx.x >> 3;   // ii in [0,96)
  const int bm = xcd * 8 + ii / 12, bn = ii % 12;
  const int tid = threadIdx.x;
  const int w = tid >> 6, lane = tid & 63;
  const int wm = w >> 1, wn = w & 1;
  const int g = lane >> 4, r16 = lane & 15;

  char* const base = LdsB + w * 16384;       // this wave's private region
  const char* Ag = (const char*)A + (size_t)(bm * 128 + wm * 64) * 2048;
  const char* Bg = (const char*)Bt + (size_t)(bn * 128 + wn * 64) * 2048;

  const f32x4 vzero = {0.f, 0.f, 0.f, 0.f};
  f32x4 acc[4][4];
#pragma unroll
  for (int i = 0; i < 4; ++i)
#pragma unroll
    for (int j = 0; j < 4; ++j) acc[i][j] = vzero;

  auto stageW = [&](int s, int k0) {
#pragma unroll
    for (int i = 0; i < 4; ++i) {
      const int u = lane + i * 64;           // 0..255
      const int row = u >> 2;                // 0..63 local row
      const int pu = (u & 3) ^ ((u >> 3) & 3);
      gload16(Ag + (size_t)row * 2048 + k0 * 2 + pu * 16, base + s * 8192 + u * 16);
    }
#pragma unroll
    for (int i = 0; i < 4; ++i) {
      const int u = lane + i * 64;
      const int row = u >> 2;
      const int pu = (u & 3) ^ ((u >> 3) & 3);
      gload16(Bg + (size_t)row * 2048 + k0 * 2 + pu * 16, base + s * 8192 + 4096 + u * 16);
    }
  };

  stageW(0, 0);
  stageW(1, 32);
  const int fsw = (g ^ ((r16 >> 1) & 3)) << 4;
  for (int t = 0; t < 32; ++t) {
    if (t < 31) { asm volatile("s_waitcnt vmcnt(8)" ::: "memory"); }
    else        { asm volatile("s_waitcnt vmcnt(0)" ::: "memory"); }
    const char* Ab = base + (t & 1) * 8192;
    const char* Bb = Ab + 4096;
    short8 af[4], bf[4];
#pragma unroll
    for (int mi = 0; mi < 4; ++mi)
      af[mi] = *(const short8*)(Ab + (mi * 16 + r16) * 64 + fsw);
#pragma unroll
    for (int ni = 0; ni < 4; ++ni)
      bf[ni] = *(const short8*)(Bb + (ni * 16 + r16) * 64 + fsw);
    __builtin_amdgcn_s_setprio(1);
#pragma unroll
    for (int mi = 0; mi < 4; ++mi)
#pragma unroll
      for (int ni = 0; ni < 4; ++ni)
        acc[mi][ni] = __builtin_amdgcn_mfma_f32_16x16x32_bf16(af[mi], bf[ni], acc[mi][ni], 0, 0, 0);
    __builtin_amdgcn_s_setprio(0);
    __builtin_amdgcn_sched_barrier(0);       // keep stage issue after MFMA cluster
    if (t + 2 < 32) stageW(t & 1, (t + 2) * 32);
  }

  float bcol[4];
#pragma unroll
  for (int ni = 0; ni < 4; ++ni) bcol[ni] = bias[bn * 128 + wn * 64 + ni * 16 + r16];
  if (bn < 8) {                              // ---- Q (pre-scaled) ----
#pragma unroll
    for (int mi = 0; mi < 4; ++mi)
#pragma unroll
      for (int ni = 0; ni < 4; ++ni) {
        const int col = bn * 128 + wn * 64 + ni * 16 + r16;
#pragma unroll
        for (int rr = 0; rr < 4; ++rr) {
          const int row = bm * 128 + wm * 64 + mi * 16 + g * 4 + rr;
          Qb[(size_t)row * 1024 + col] = f2bf((acc[mi][ni][rr] + bcol[ni]) * 0.180336881f);
        }
      }
  } else if (bn < 10) {                      // ---- K ----
#pragma unroll
    for (int mi = 0; mi < 4; ++mi)
#pragma unroll
      for (int ni = 0; ni < 4; ++ni) {
        const int c = bn * 128 + wn * 64 + ni * 16 + r16 - 1024;
        const int gi = c >> 6, dd = c & 63;
#pragma unroll
        for (int rr = 0; rr < 4; ++rr) {
          const int row = bm * 128 + wm * 64 + mi * 16 + g * 4 + rr;
          const int bb = row >> 11, s = row & 2047;
          Kb[((size_t)(bb * 4 + gi) * 2048 + s) * 64 + dd] = f2bf(acc[mi][ni][rr] + bcol[ni]);
        }
      }
  } else {                                   // ---- V -> transposed, kappa-permuted ----
#pragma unroll
    for (int mi = 0; mi < 4; ++mi) {
      const int row0 = bm * 128 + wm * 64 + mi * 16 + g * 4;
      const int bb = row0 >> 11;
      const int s = row0 & 2047;
      const int pos = (s & ~31) + g * 8 + (mi & 1) * 4;   // kappa position of rr=0
#pragma unroll
      for (int ni = 0; ni < 4; ++ni) {
        const int c = bn * 128 + wn * 64 + ni * 16 + r16 - 1280;
        const int gi = c >> 6, dd = c & 63;
        ushort4v pk;
#pragma unroll
        for (int rr = 0; rr < 4; ++rr) pk[rr] = f2bf(acc[mi][ni][rr] + bcol[ni]);
        *reinterpret_cast<ushort4v*>(Vt + ((size_t)(bb * 4 + gi) * 64 + dd) * 2048 + pos) = pk;
      }
    }
  }
}

// ---------- output GEMM (round-7/13 proven structure) ----------
__global__ __launch_bounds__(256, 3) void gemm_out_kernel(
    const ushort_t* __restrict__ A, const ushort_t* __restrict__ Bt,
    const float* __restrict__ bias, float* __restrict__ Cout)
{
  __shared__ __align__(16) char LdsB[49152];
  const int xcd = blockIdx.x & 7, ii = blockIdx.x >> 3;   // ii in [0,64)
  const int bm = xcd * 8 + (ii >> 3), bn = ii & 7;
  const int tid = threadIdx.x;
  const int w = tid >> 6, lane = tid & 63;
  const int wm = w >> 1, wn = w & 1;
  const int g = lane >> 4, r16 = lane & 15;

  const f32x4 vzero = {0.f, 0.f, 0.f, 0.f};
  f32x4 acc[4][4];
#pragma unroll
  for (int i = 0; i < 4; ++i)
#pragma unroll
    for (int j = 0; j < 4; ++j) acc[i][j] = vzero;
  auto stage = [&](int s, int k0) {
    char* base = LdsB + s * 16384;
#pragma unroll
    for (int i = 0; i < 2; ++i) {
      const int u = tid + i * 256;
      const int row = u >> 2;
      const int pu = (u & 3) ^ ((u >> 3) & 3);
      gload16((const char*)A + (size_t)(bm * 128 + row) * 2048 + k0 * 2 + pu * 16,
              base + u * 16);
    }
#pragma unroll
    for (int i = 0; i < 2; ++i) {
      const int u = tid + i * 256;
      const int row = u >> 2;
      const int pu = (u & 3) ^ ((u >> 3) & 3);
      gload16((const char*)Bt + (size_t)(bn * 128 + row) * 2048 + k0 * 2 + pu * 16,
              base + 8192 + u * 16);
    }
  };
  stage(0, 0);
  stage(1, 32);
  const int fsw = (g ^ ((r16 >> 1) & 3)) << 4;
  for (int t = 0; t < 32; ++t) {
    if (t < 31) { asm volatile("s_waitcnt vmcnt(4) lgkmcnt(0)" ::: "memory"); }
    else        { asm volatile("s_waitcnt vmcnt(0) lgkmcnt(0)" ::: "memory"); }
    __builtin_amdgcn_s_barrier();
    if (t + 2 < 32) stage((t + 2) % 3, (t + 2) * 32);
    const char* Ab = LdsB + (t % 3) * 16384;
    const char* Bb = Ab + 8192;
    short8 af[4], bf[4];
#pragma unroll
    for (int mi = 0; mi < 4; ++mi)
      af[mi] = *(const short8*)(Ab + (wm * 64 + mi * 16 + r16) * 64 + fsw);
#pragma unroll
    for (int ni = 0; ni < 4; ++ni)
      bf[ni] = *(const short8*)(Bb + (wn * 64 + ni * 16 + r16) * 64 + fsw);
    __builtin_amdgcn_s_setprio(1);
#pragma unroll
    for (int mi = 0; mi < 4; ++mi)
#pragma unroll
      for (int ni = 0; ni < 4; ++ni)
        acc[mi][ni] = __builtin_amdgcn_mfma_f32_16x16x32_bf16(af[mi], bf[ni], acc[mi][ni], 0, 0, 0);
    __builtin_amdgcn_s_setprio(0);
  }

  float bcol[4];
#pragma unroll
  for (int ni = 0; ni < 4; ++ni) bcol[ni] = bias[bn * 128 + wn * 64 + ni * 16 + r16];
#pragma unroll
  for (int mi = 0; mi < 4; ++mi)
#pragma unroll
    for (int ni = 0; ni < 4; ++ni) {
      const int col = bn * 128 + wn * 64 + ni * 16 + r16;
#pragma unroll
      for (int rr = 0; rr < 4; ++rr) {
        const int row = bm * 128 + wm * 64 + mi * 16 + g * 4 + rr;
        Cout[(size_t)row * 1024 + col] = acc[mi][ni][rr] + bcol[ni];
      }
    }
}

// ---------- attention (round-13 proven) ----------
__global__ __launch_bounds__(256, 2) void attn_kernel(
    const ushort_t* __restrict__ Qb, const ushort_t* __restrict__ Kb,
    const ushort_t* __restrict__ Vt, ushort_t* __restrict__ attout)
{
  __shared__ __align__(16) char KsB[24576];  // 3 x [64 keys][128B], swz (key&7)
  __shared__ __align__(16) char VsB[24576];  // 3 x [64 d][128B], swz (d&7), keys kappa-permuted
  const int fid = blockIdx.x;
  const int lo = fid & 7, hi = fid >> 3;     // hi in [0,64)
  const int qt = 31 - (hi & 31);
  const int gb = lo | ((hi >> 5) << 3);      // 0..15
  const int gg = gb & 3, b = gb >> 2;

  const int tid = threadIdx.x;
  const int w = tid >> 6, lane = tid & 63;
  const int g = lane >> 4, r16 = lane & 15;
  const int q0w = qt * 64 + w * 16;

  short8 qf[4][2];
#pragma unroll
  for (int hh = 0; hh < 4; ++hh) {
    const int h = gg * 4 + hh;
    const char* qptr = (const char*)Qb + ((size_t)(b * 2048 + q0w + r16) * 1024 + h * 64) * 2;
#pragma unroll
    for (int dc = 0; dc < 2; ++dc)
      qf[hh][dc] = *(const short8*)(qptr + dc * 64 + g * 16);
  }

  const f32x4 vzero = {0.f, 0.f, 0.f, 0.f};
  f32x4 accO[4][4];
#pragma unroll
  for (int hh = 0; hh < 4; ++hh)
#pragma unroll
    for (int nt = 0; nt < 4; ++nt) accO[hh][nt] = vzero;
  float lsum[4] = {0.f, 0.f, 0.f, 0.f};

  const char* KbB = (const char*)Kb + (size_t)(b * 4 + gg) * 2048 * 128;
  const char* VtB = (const char*)Vt + (size_t)(b * 4 + gg) * 64 * 4096;

  const int kb0 = (qt >= 8) ? (qt * 64 - 512) : 0;
  const int NT = (qt * 64 + 64 - kb0) >> 6;  // 1..9

  auto stage = [&](int buf, int kb) {
#pragma unroll
    for (int i = 0; i < 2; ++i) {
      const int u = tid + i * 256;
      const int row = u >> 3, phys = u & 7;
      gload16(KbB + (size_t)(kb + row) * 128 + ((phys ^ (row & 7)) << 4),
              KsB + buf * 8192 + u * 16);
    }
#pragma unroll
    for (int i = 0; i < 2; ++i) {
      const int u = tid + i * 256;
      const int row = u >> 3, phys = u & 7;
      gload16(VtB + (size_t)row * 4096 + (size_t)kb * 2 + ((phys ^ (row & 7)) << 4),
              VsB + buf * 8192 + u * 16);
    }
  };

  stage(0, kb0);
  if (NT > 1) stage(1, kb0 + 64);
  for (int t = 0; t < NT; ++t) {
    if (t < NT - 1) { asm volatile("s_waitcnt vmcnt(4) lgkmcnt(0)" ::: "memory"); }
    else            { asm volatile("s_waitcnt vmcnt(0) lgkmcnt(0)" ::: "memory"); }
    __builtin_amdgcn_s_barrier();
    if (t + 2 < NT) stage((t + 2) % 3, kb0 + (t + 2) * 64);
    const int kb = kb0 + t * 64;
    const char* Ks = KsB + (t % 3) * 8192;
    const char* Vs = VsB + (t % 3) * 8192;

    f32x4 st[4][4];
#pragma unroll
    for (int ki = 0; ki < 4; ++ki) {
      const int key = ki * 16 + r16;
      const int swz = key & 7;
      const short8 kf0 = *(const short8*)(Ks + key * 128 + ((g ^ swz) << 4));
      const short8 kf1 = *(const short8*)(Ks + key * 128 + (((4 + g) ^ swz) << 4));
#pragma unroll
      for (int hh = 0; hh < 4; ++hh) {
        st[hh][ki] = __builtin_amdgcn_mfma_f32_16x16x32_bf16(kf0, qf[hh][0], vzero, 0, 0, 0);
        st[hh][ki] = __builtin_amdgcn_mfma_f32_16x16x32_bf16(kf1, qf[hh][1], st[hh][ki], 0, 0, 0);
      }
    }

    const bool full = (kb >= q0w - 496) && (kb <= q0w - 63);   // wave-uniform
    if (full) {
#pragma unroll
      for (int hh = 0; hh < 4; ++hh)
#pragma unroll
        for (int ki = 0; ki < 4; ++ki)
#pragma unroll
          for (int r = 0; r < 4; ++r)
            st[hh][ki][r] = __builtin_amdgcn_exp2f(st[hh][ki][r]);
    } else {
      const int q = q0w + r16;
#pragma unroll
      for (int ki = 0; ki < 4; ++ki)
#pragma unroll
        for (int r = 0; r < 4; ++r) {
          const int key = kb + ki * 16 + g * 4 + r;
          const bool valid = (key <= q) && (key + 512 > q);
#pragma unroll
          for (int hh = 0; hh < 4; ++hh)
            st[hh][ki][r] = __builtin_amdgcn_exp2f(valid ? st[hh][ki][r] : -INFINITY);
        }
    }
    PFrag pf[4][2];
#pragma unroll
    for (int hh = 0; hh < 4; ++hh) {
      float tk[4];
#pragma unroll
      for (int ki = 0; ki < 4; ++ki)
        tk[ki] = (st[hh][ki][0] + st[hh][ki][1]) + (st[hh][ki][2] + st[hh][ki][3]);
      lsum[hh] += (tk[0] + tk[1]) + (tk[2] + tk[3]);
#pragma unroll
      for (int c = 0; c < 2; ++c)
#pragma unroll
        for (int pr = 0; pr < 2; ++pr) {
          asm("v_cvt_pk_bf16_f32 %0, %1, %2"
              : "=v"(pf[hh][c].w[pr * 2])
              : "v"(st[hh][2 * c + pr][0]), "v"(st[hh][2 * c + pr][1]));
          asm("v_cvt_pk_bf16_f32 %0, %1, %2"
              : "=v"(pf[hh][c].w[pr * 2 + 1])
              : "v"(st[hh][2 * c + pr][2]), "v"(st[hh][2 * c + pr][3]));
        }
    }

#pragma unroll
    for (int c = 0; c < 2; ++c)
#pragma unroll
      for (int nt = 0; nt < 4; ++nt) {
        const int d = nt * 16 + r16;
        const short8 vf = *(const short8*)(Vs + d * 128 + (((c * 4 + g) ^ (d & 7)) << 4));
#pragma unroll
        for (int hh = 0; hh < 4; ++hh)
          accO[hh][nt] = __builtin_amdgcn_mfma_f32_16x16x32_bf16(pf[hh][c].v, vf, accO[hh][nt], 0, 0, 0);
      }
  }

#pragma unroll
  for (int hh = 0; hh < 4; ++hh) {
    float ts = lsum[hh];
    ts += __shfl_xor(ts, 16);
    ts += __shfl_xor(ts, 32);
    const float linv = 1.f / ts;
    float lq[4];
#pragma unroll
    for (int rr = 0; rr < 4; ++rr) lq[rr] = __shfl(linv, g * 4 + rr);
    const int h = gg * 4 + hh;
#pragma unroll
    for (int nt = 0; nt < 4; ++nt) {
      const int ocol = h * 64 + nt * 16 + r16;
#pragma unroll
      for (int rr = 0; rr < 4; ++rr) {
        const int orow = b * 2048 + q0w + g * 4 + rr;
        attout[(size_t)orow * 1024 + ocol] = f2bf(accO[hh][nt][rr] * lq[rr]);
      }
    }
  }
}

// ---------- launch ----------
extern "C" void kernel_launch(void* const* d_in, const int* in_sizes, int n_in,
                              void* d_out, int out_size, void* d_ws, size_t ws_size,
                              hipStream_t stream) {
  (void)in_sizes; (void)n_in; (void)out_size; (void)ws_size;
  const float* x  = (const float*)d_in[0];
  const float* Wq = (const float*)d_in[1];
  const float* bq = (const float*)d_in[2];
  const float* Wk = (const float*)d_in[3];
  const float* bk = (const float*)d_in[4];
  const float* Wv = (const float*)d_in[5];
  const float* bv = (const float*)d_in[6];
  const float* Wo = (const float*)d_in[7];
  const float* bo = (const float*)d_in[8];

  char* ws = (char*)d_ws;
  ushort_t* Qb   = (ushort_t*)(ws + 0);          // 8192x1024 bf16 = 16 MiB
  ushort_t* Kb   = (ushort_t*)(ws + 16777216);   // 16x2048x64 bf16 = 4 MiB
  ushort_t* Vt   = (ushort_t*)(ws + 20971520);   // 16x64x2048 bf16 = 4 MiB
  ushort_t* wt   = (ushort_t*)(ws + 25165824);   // 2560x1024 bf16 = 5 MiB
  float*    bqkv = (float*)   (ws + 30408704);   // 1536 fp32
  ushort_t* xb   = (ushort_t*)(ws + 30416896);   // 8192x1024 bf16 = 16 MiB
  ushort_t* att  = (ushort_t*)(ws + 47194112);   // 8192x1024 bf16 = 16 MiB

  prep_kernel<<<10752, 256, 0, stream>>>(x, xb, Wq, Wk, Wv, Wo, bq, bk, bv, wt, bqkv);
  gemm_qkv_kernel<<<768, 256, 0, stream>>>(xb, wt, bqkv, Qb, Kb, Vt);
  attn_kernel<<<512, 256, 0, stream>>>(Qb, Kb, Vt, att);
  gemm_out_kernel<<<512, 256, 0, stream>>>(att, wt + (size_t)1536 * 1024, bo, (float*)d_out);
}

// Round 16
// 97.287 us; speedup vs baseline: 1.0992x; 1.0992x over previous
//
#include <hip/hip_runtime.h>
#include <cstdint>
#include <cstddef>

// ---------- types ----------
typedef __attribute__((ext_vector_type(8))) short short8;
typedef __attribute__((ext_vector_type(4))) float f32x4;
typedef __attribute__((ext_vector_type(4))) unsigned short ushort4v;
typedef __attribute__((ext_vector_type(8))) unsigned short ushort8v;
typedef unsigned short ushort_t;

union PFrag { unsigned int w[4]; short8 v; };

__device__ __forceinline__ ushort_t f2bf(float f) {
  unsigned int u = __builtin_bit_cast(unsigned int, f);
  u += 0x7FFFu + ((u >> 16) & 1u);   // RNE; inputs finite
  return (ushort_t)(u >> 16);
}

__device__ __forceinline__ void gload16(const void* g, void* l) {
  __builtin_amdgcn_global_load_lds(
      (const __attribute__((address_space(1))) unsigned int*)g,
      (__attribute__((address_space(3))) unsigned int*)l, 16, 0, 0);
}

// ---------- merged prep kernel ----------
// Blocks [0, 4096): cast x fp32 -> bf16, 8 floats/thread (16B read + 16B
// write per lane).  Blocks [4096, 6656): tiled transpose W[k][n] fp32 ->
// Wt[n][k] bf16 (+ bias concat on the tk==0 row).  Wt rows: 0..1023 Wq^T,
// 1024..1279 Wk^T, 1280..1535 Wv^T, 1536..2559 Wo^T.
__global__ __launch_bounds__(256) void prep_kernel(
    const float* __restrict__ x, ushort_t* __restrict__ xb,
    const float* __restrict__ Wq, const float* __restrict__ Wk,
    const float* __restrict__ Wv, const float* __restrict__ Wo,
    const float* __restrict__ bq, const float* __restrict__ bk,
    const float* __restrict__ bv, ushort_t* __restrict__ Wt,
    float* __restrict__ bqkv) {
  __shared__ float tile[32][33];
  const int t = threadIdx.x;
  if (blockIdx.x < 4096) {
    const int i = (blockIdx.x * 256 + t) * 8;
    const float4 v0 = *reinterpret_cast<const float4*>(x + i);
    const float4 v1 = *reinterpret_cast<const float4*>(x + i + 4);
    ushort8v r = { f2bf(v0.x), f2bf(v0.y), f2bf(v0.z), f2bf(v0.w),
                   f2bf(v1.x), f2bf(v1.y), f2bf(v1.z), f2bf(v1.w) };
    *reinterpret_cast<ushort8v*>(xb + i) = r;
    return;
  }
  const int bid = blockIdx.x - 4096;          // 0..2559
  const int tn = bid % 80, tk = bid / 80;
  if (tk == 0) {
    const int u = tn * 256 + t;
    if (u < 1536) bqkv[u] = (u < 1024) ? bq[u] : (u < 1280) ? bk[u - 1024] : bv[u - 1280];
  }
  const int n0 = tn * 32;
  const float* W; int ldn, nloc;
  if      (n0 < 1024) { W = Wq; ldn = 1024; nloc = n0; }
  else if (n0 < 1280) { W = Wk; ldn = 256;  nloc = n0 - 1024; }
  else if (n0 < 1536) { W = Wv; ldn = 256;  nloc = n0 - 1280; }
  else                { W = Wo; ldn = 1024; nloc = n0 - 1536; }
  const int sr = t >> 3, sc = (t & 7) * 4;
  const float4 v = *reinterpret_cast<const float4*>(W + (size_t)(tk * 32 + sr) * ldn + nloc + sc);
  tile[sr][sc] = v.x; tile[sr][sc + 1] = v.y; tile[sr][sc + 2] = v.z; tile[sr][sc + 3] = v.w;
  __syncthreads();
  const int wr = t >> 3, wc = (t & 7) * 4;
  ushort4v o = { f2bf(tile[wc][wr]), f2bf(tile[wc + 1][wr]),
                 f2bf(tile[wc + 2][wr]), f2bf(tile[wc + 3][wr]) };
  *reinterpret_cast<ushort4v*>(Wt + (size_t)(n0 + wr) * 1024 + tk * 32 + wc) = o;
}

// ---------- GEMM core (round-7/13 proven: best measured) ----------
// Block tile 128x128, BK=32, 4 waves (2x2), per-wave 64x64 (acc[4][4]),
// 16x16x32 bf16 MFMA.  3-stage LDS pipeline (16 KB/stage, 48 KB -> 3/CU),
// counted s_waitcnt vmcnt(4), raw s_barrier, setprio around the MFMA cluster.
#define GEMM_IDS \
  const int tid = threadIdx.x;                        \
  const int w = tid >> 6, lane = tid & 63;            \
  const int wm = w >> 1, wn = w & 1;                  \
  const int g = lane >> 4, r16 = lane & 15;

#define GEMM_KLOOP(APTR, BPTR)                                                          \
  const f32x4 vzero = {0.f, 0.f, 0.f, 0.f};                                             \
  f32x4 acc[4][4];                                                                      \
  _Pragma("unroll") for (int i = 0; i < 4; ++i)                                         \
    _Pragma("unroll") for (int j = 0; j < 4; ++j) acc[i][j] = vzero;                    \
  auto stage = [&](int s, int k0) {                                                     \
    char* base = LdsB + s * 16384;                                                      \
    _Pragma("unroll") for (int i = 0; i < 2; ++i) {                                     \
      const int u = tid + i * 256;                                                      \
      const int row = u >> 2;                                                           \
      const int pu = (u & 3) ^ ((u >> 3) & 3);                                          \
      gload16((const char*)(APTR) + (size_t)(bm * 128 + row) * 2048 + k0 * 2 + pu * 16, \
              base + u * 16);                                                           \
    }                                                                                   \
    _Pragma("unroll") for (int i = 0; i < 2; ++i) {                                     \
      const int u = tid + i * 256;                                                      \
      const int row = u >> 2;                                                           \
      const int pu = (u & 3) ^ ((u >> 3) & 3);                                          \
      gload16((const char*)(BPTR) + (size_t)(bn * 128 + row) * 2048 + k0 * 2 + pu * 16, \
              base + 8192 + u * 16);                                                    \
    }                                                                                   \
  };                                                                                    \
  stage(0, 0);                                                                          \
  stage(1, 32);                                                                         \
  const int fsw = (g ^ ((r16 >> 1) & 3)) << 4;                                          \
  for (int t = 0; t < 32; ++t) {                                                        \
    if (t < 31) { asm volatile("s_waitcnt vmcnt(4) lgkmcnt(0)" ::: "memory"); }         \
    else        { asm volatile("s_waitcnt vmcnt(0) lgkmcnt(0)" ::: "memory"); }         \
    __builtin_amdgcn_s_barrier();                                                       \
    if (t + 2 < 32) stage((t + 2) % 3, (t + 2) * 32);                                   \
    const char* Ab = LdsB + (t % 3) * 16384;                                            \
    const char* Bb = Ab + 8192;                                                         \
    short8 af[4], bf[4];                                                                \
    _Pragma("unroll") for (int mi = 0; mi < 4; ++mi)                                    \
      af[mi] = *(const short8*)(Ab + (wm * 64 + mi * 16 + r16) * 64 + fsw);             \
    _Pragma("unroll") for (int ni = 0; ni < 4; ++ni)                                    \
      bf[ni] = *(const short8*)(Bb + (wn * 64 + ni * 16 + r16) * 64 + fsw);             \
    __builtin_amdgcn_s_setprio(1);                                                      \
    _Pragma("unroll") for (int mi = 0; mi < 4; ++mi)                                    \
      _Pragma("unroll") for (int ni = 0; ni < 4; ++ni)                                  \
        acc[mi][ni] = __builtin_amdgcn_mfma_f32_16x16x32_bf16(af[mi], bf[ni], acc[mi][ni], 0, 0, 0); \
    __builtin_amdgcn_s_setprio(0);                                                      \
  }

// QKV GEMM: M=8192, N=1536, K=1024.  Writes Qb [8192][1024] (pre-scaled by
// 0.125*log2e), Kb [b*4+g][2048][64], Vt [b*4+g][64][2048] key-permuted to
// MFMA kappa order within each 32-key chunk.
__global__ __launch_bounds__(256, 3) void gemm_qkv_kernel(
    const ushort_t* __restrict__ A, const ushort_t* __restrict__ Bt,
    const float* __restrict__ bias,
    ushort_t* __restrict__ Qb, ushort_t* __restrict__ Kb, ushort_t* __restrict__ Vt)
{
  __shared__ __align__(16) char LdsB[49152];
  const int xcd = blockIdx.x & 7, ii = blockIdx.x >> 3;   // ii in [0,96)
  const int bm = xcd * 8 + ii / 12, bn = ii % 12;
  GEMM_IDS
  GEMM_KLOOP(A, Bt)

  float bcol[4];
#pragma unroll
  for (int ni = 0; ni < 4; ++ni) bcol[ni] = bias[bn * 128 + wn * 64 + ni * 16 + r16];
  if (bn < 8) {                              // ---- Q (pre-scaled) ----
#pragma unroll
    for (int mi = 0; mi < 4; ++mi)
#pragma unroll
      for (int ni = 0; ni < 4; ++ni) {
        const int col = bn * 128 + wn * 64 + ni * 16 + r16;
#pragma unroll
        for (int rr = 0; rr < 4; ++rr) {
          const int row = bm * 128 + wm * 64 + mi * 16 + g * 4 + rr;
          Qb[(size_t)row * 1024 + col] = f2bf((acc[mi][ni][rr] + bcol[ni]) * 0.180336881f);
        }
      }
  } else if (bn < 10) {                      // ---- K ----
#pragma unroll
    for (int mi = 0; mi < 4; ++mi)
#pragma unroll
      for (int ni = 0; ni < 4; ++ni) {
        const int c = bn * 128 + wn * 64 + ni * 16 + r16 - 1024;
        const int gi = c >> 6, dd = c & 63;
#pragma unroll
        for (int rr = 0; rr < 4; ++rr) {
          const int row = bm * 128 + wm * 64 + mi * 16 + g * 4 + rr;
          const int bb = row >> 11, s = row & 2047;
          Kb[((size_t)(bb * 4 + gi) * 2048 + s) * 64 + dd] = f2bf(acc[mi][ni][rr] + bcol[ni]);
        }
      }
  } else {                                   // ---- V -> transposed, kappa-permuted ----
#pragma unroll
    for (int mi = 0; mi < 4; ++mi) {
      const int row0 = bm * 128 + wm * 64 + mi * 16 + g * 4;
      const int bb = row0 >> 11;
      const int s = row0 & 2047;
      const int pos = (s & ~31) + g * 8 + (mi & 1) * 4;   // kappa position of rr=0
#pragma unroll
      for (int ni = 0; ni < 4; ++ni) {
        const int c = bn * 128 + wn * 64 + ni * 16 + r16 - 1280;
        const int gi = c >> 6, dd = c & 63;
        ushort4v pk;
#pragma unroll
        for (int rr = 0; rr < 4; ++rr) pk[rr] = f2bf(acc[mi][ni][rr] + bcol[ni]);
        *reinterpret_cast<ushort4v*>(Vt + ((size_t)(bb * 4 + gi) * 64 + dd) * 2048 + pos) = pk;
      }
    }
  }
}

// Output GEMM: M=8192, N=1024, K=1024, fp32 out + bias.
__global__ __launch_bounds__(256, 3) void gemm_out_kernel(
    const ushort_t* __restrict__ A, const ushort_t* __restrict__ Bt,
    const float* __restrict__ bias, float* __restrict__ Cout)
{
  __shared__ __align__(16) char LdsB[49152];
  const int xcd = blockIdx.x & 7, ii = blockIdx.x >> 3;   // ii in [0,64)
  const int bm = xcd * 8 + (ii >> 3), bn = ii & 7;
  GEMM_IDS
  GEMM_KLOOP(A, Bt)

  float bcol[4];
#pragma unroll
  for (int ni = 0; ni < 4; ++ni) bcol[ni] = bias[bn * 128 + wn * 64 + ni * 16 + r16];
#pragma unroll
  for (int mi = 0; mi < 4; ++mi)
#pragma unroll
    for (int ni = 0; ni < 4; ++ni) {
      const int col = bn * 128 + wn * 64 + ni * 16 + r16;
#pragma unroll
      for (int rr = 0; rr < 4; ++rr) {
        const int row = bm * 128 + wm * 64 + mi * 16 + g * 4 + rr;
        Cout[(size_t)row * 1024 + col] = acc[mi][ni][rr] + bcol[ni];
      }
    }
}

// ---------- attention (round-13 proven) ----------
// Block = (64-query tile, group, batch); 4 waves = 4 query-subtiles of 16.
// Each wave computes ALL 4 heads of its group; KVBLK=64, 3-stage counted-
// vmcnt pipeline, static-max softmax (Q pre-scaled), mask-free interior
// path, kappa-permuted Vt.  Grid 512 = 2 blocks/CU (2 barrier domains).
__global__ __launch_bounds__(256, 2) void attn_kernel(
    const ushort_t* __restrict__ Qb, const ushort_t* __restrict__ Kb,
    const ushort_t* __restrict__ Vt, ushort_t* __restrict__ attout)
{
  __shared__ __align__(16) char KsB[24576];  // 3 x [64 keys][128B], swz (key&7)
  __shared__ __align__(16) char VsB[24576];  // 3 x [64 d][128B], swz (d&7), keys kappa-permuted
  const int fid = blockIdx.x;
  const int lo = fid & 7, hi = fid >> 3;     // hi in [0,64)
  const int qt = 31 - (hi & 31);             // long blocks dispatch-early
  const int gb = lo | ((hi >> 5) << 3);      // 0..15; XCD gets 2 (g,b) pairs
  const int gg = gb & 3, b = gb >> 2;

  const int tid = threadIdx.x;
  const int w = tid >> 6, lane = tid & 63;
  const int g = lane >> 4, r16 = lane & 15;
  const int q0w = qt * 64 + w * 16;          // this wave's 16 queries

  short8 qf[4][2];
#pragma unroll
  for (int hh = 0; hh < 4; ++hh) {
    const int h = gg * 4 + hh;
    const char* qptr = (const char*)Qb + ((size_t)(b * 2048 + q0w + r16) * 1024 + h * 64) * 2;
#pragma unroll
    for (int dc = 0; dc < 2; ++dc)
      qf[hh][dc] = *(const short8*)(qptr + dc * 64 + g * 16);
  }

  const f32x4 vzero = {0.f, 0.f, 0.f, 0.f};
  f32x4 accO[4][4];
#pragma unroll
  for (int hh = 0; hh < 4; ++hh)
#pragma unroll
    for (int nt = 0; nt < 4; ++nt) accO[hh][nt] = vzero;
  float lsum[4] = {0.f, 0.f, 0.f, 0.f};

  const char* KbB = (const char*)Kb + (size_t)(b * 4 + gg) * 2048 * 128;  // key rows 128B
  const char* VtB = (const char*)Vt + (size_t)(b * 4 + gg) * 64 * 4096;   // d rows 4096B

  const int kb0 = (qt >= 8) ? (qt * 64 - 512) : 0;
  const int NT = (qt * 64 + 64 - kb0) >> 6;  // 1..9

  auto stage = [&](int buf, int kb) {
#pragma unroll
    for (int i = 0; i < 2; ++i) {
      const int u = tid + i * 256;           // 0..511
      const int row = u >> 3, phys = u & 7;
      gload16(KbB + (size_t)(kb + row) * 128 + ((phys ^ (row & 7)) << 4),
              KsB + buf * 8192 + u * 16);
    }
#pragma unroll
    for (int i = 0; i < 2; ++i) {
      const int u = tid + i * 256;
      const int row = u >> 3, phys = u & 7;  // row = d
      gload16(VtB + (size_t)row * 4096 + (size_t)kb * 2 + ((phys ^ (row & 7)) << 4),
              VsB + buf * 8192 + u * 16);
    }
  };

  stage(0, kb0);
  if (NT > 1) stage(1, kb0 + 64);
  for (int t = 0; t < NT; ++t) {
    if (t < NT - 1) { asm volatile("s_waitcnt vmcnt(4) lgkmcnt(0)" ::: "memory"); }
    else            { asm volatile("s_waitcnt vmcnt(0) lgkmcnt(0)" ::: "memory"); }
    __builtin_amdgcn_s_barrier();
    if (t + 2 < NT) stage((t + 2) % 3, kb0 + (t + 2) * 64);
    const int kb = kb0 + t * 64;
    const char* Ks = KsB + (t % 3) * 8192;
    const char* Vs = VsB + (t % 3) * 8192;

    f32x4 st[4][4];
#pragma unroll
    for (int ki = 0; ki < 4; ++ki) {
      const int key = ki * 16 + r16;
      const int swz = key & 7;
      const short8 kf0 = *(const short8*)(Ks + key * 128 + ((g ^ swz) << 4));
      const short8 kf1 = *(const short8*)(Ks + key * 128 + (((4 + g) ^ swz) << 4));
#pragma unroll
      for (int hh = 0; hh < 4; ++hh) {
        st[hh][ki] = __builtin_amdgcn_mfma_f32_16x16x32_bf16(kf0, qf[hh][0], vzero, 0, 0, 0);
        st[hh][ki] = __builtin_amdgcn_mfma_f32_16x16x32_bf16(kf1, qf[hh][1], st[hh][ki], 0, 0, 0);
      }
    }

    const bool full = (kb >= q0w - 496) && (kb <= q0w - 63);   // wave-uniform
    if (full) {
#pragma unroll
      for (int hh = 0; hh < 4; ++hh)
#pragma unroll
        for (int ki = 0; ki < 4; ++ki)
#pragma unroll
          for (int r = 0; r < 4; ++r)
            st[hh][ki][r] = __builtin_amdgcn_exp2f(st[hh][ki][r]);
    } else {
      const int q = q0w + r16;
#pragma unroll
      for (int ki = 0; ki < 4; ++ki)
#pragma unroll
        for (int r = 0; r < 4; ++r) {
          const int key = kb + ki * 16 + g * 4 + r;
          const bool valid = (key <= q) && (key + 512 > q);
#pragma unroll
          for (int hh = 0; hh < 4; ++hh)
            st[hh][ki][r] = __builtin_amdgcn_exp2f(valid ? st[hh][ki][r] : -INFINITY);
        }
    }
    PFrag pf[4][2];
#pragma unroll
    for (int hh = 0; hh < 4; ++hh) {
      float tk[4];
#pragma unroll
      for (int ki = 0; ki < 4; ++ki)
        tk[ki] = (st[hh][ki][0] + st[hh][ki][1]) + (st[hh][ki][2] + st[hh][ki][3]);
      lsum[hh] += (tk[0] + tk[1]) + (tk[2] + tk[3]);
#pragma unroll
      for (int c = 0; c < 2; ++c)
#pragma unroll
        for (int pr = 0; pr < 2; ++pr) {
          asm("v_cvt_pk_bf16_f32 %0, %1, %2"
              : "=v"(pf[hh][c].w[pr * 2])
              : "v"(st[hh][2 * c + pr][0]), "v"(st[hh][2 * c + pr][1]));
          asm("v_cvt_pk_bf16_f32 %0, %1, %2"
              : "=v"(pf[hh][c].w[pr * 2 + 1])
              : "v"(st[hh][2 * c + pr][2]), "v"(st[hh][2 * c + pr][3]));
        }
    }

#pragma unroll
    for (int c = 0; c < 2; ++c)
#pragma unroll
      for (int nt = 0; nt < 4; ++nt) {
        const int d = nt * 16 + r16;
        const short8 vf = *(const short8*)(Vs + d * 128 + (((c * 4 + g) ^ (d & 7)) << 4));
#pragma unroll
        for (int hh = 0; hh < 4; ++hh)
          accO[hh][nt] = __builtin_amdgcn_mfma_f32_16x16x32_bf16(pf[hh][c].v, vf, accO[hh][nt], 0, 0, 0);
      }
  }

#pragma unroll
  for (int hh = 0; hh < 4; ++hh) {
    float ts = lsum[hh];
    ts += __shfl_xor(ts, 16);
    ts += __shfl_xor(ts, 32);
    const float linv = 1.f / ts;
    float lq[4];
#pragma unroll
    for (int rr = 0; rr < 4; ++rr) lq[rr] = __shfl(linv, g * 4 + rr);
    const int h = gg * 4 + hh;
#pragma unroll
    for (int nt = 0; nt < 4; ++nt) {
      const int ocol = h * 64 + nt * 16 + r16;
#pragma unroll
      for (int rr = 0; rr < 4; ++rr) {
        const int orow = b * 2048 + q0w + g * 4 + rr;
        attout[(size_t)orow * 1024 + ocol] = f2bf(accO[hh][nt][rr] * lq[rr]);
      }
    }
  }
}

// ---------- launch ----------
extern "C" void kernel_launch(void* const* d_in, const int* in_sizes, int n_in,
                              void* d_out, int out_size, void* d_ws, size_t ws_size,
                              hipStream_t stream) {
  (void)in_sizes; (void)n_in; (void)out_size; (void)ws_size;
  const float* x  = (const float*)d_in[0];
  const float* Wq = (const float*)d_in[1];
  const float* bq = (const float*)d_in[2];
  const float* Wk = (const float*)d_in[3];
  const float* bk = (const float*)d_in[4];
  const float* Wv = (const float*)d_in[5];
  const float* bv = (const float*)d_in[6];
  const float* Wo = (const float*)d_in[7];
  const float* bo = (const float*)d_in[8];

  char* ws = (char*)d_ws;
  ushort_t* Qb   = (ushort_t*)(ws + 0);          // 8192x1024 bf16 = 16 MiB
  ushort_t* Kb   = (ushort_t*)(ws + 16777216);   // 16x2048x64 bf16 = 4 MiB
  ushort_t* Vt   = (ushort_t*)(ws + 20971520);   // 16x64x2048 bf16 = 4 MiB
  ushort_t* wt   = (ushort_t*)(ws + 25165824);   // 2560x1024 bf16 = 5 MiB
  float*    bqkv = (float*)   (ws + 30408704);   // 1536 fp32
  ushort_t* xb   = (ushort_t*)(ws + 30416896);   // 8192x1024 bf16 = 16 MiB
  ushort_t* att  = (ushort_t*)(ws + 47194112);   // 8192x1024 bf16 = 16 MiB

  prep_kernel<<<6656, 256, 0, stream>>>(x, xb, Wq, Wk, Wv, Wo, bq, bk, bv, wt, bqkv);
  gemm_qkv_kernel<<<768, 256, 0, stream>>>(xb, wt, bqkv, Qb, Kb, Vt);
  attn_kernel<<<512, 256, 0, stream>>>(Qb, Kb, Vt, att);
  gemm_out_kernel<<<512, 256, 0, stream>>>(att, wt + (size_t)1536 * 1024, bo, (float*)d_out);
}